// Round 6
// baseline (122.718 us; speedup 1.0000x reference)
//
#include <hip/hip_runtime.h>
#include <hip/hip_bf16.h>
#include <cstdint>

// MultiRelationalGraphDiffusion: out = LeakyReLU( sum_k conv_w[k] * (adj_norm^k @ (h@W^T)) + conv_b )
// B=8, N=2048, D=256, K=4.
//
// Round-6 restructure (R5 attribution: ~40us unexplained -> adjq re-reads + latency-gated
// diffuse at 2 blk/CU + separate 134MB normadj pass):
//  - k_htrans:   unchanged (bf16x3 MFMA, fp32-grade dominant term).
//  - k_diffuse1: FUSED rowsum+quantize+bmm. Phase 0: block reads its 64 adj rows (512KB)
//                for rowsums. K-loop: re-read (L3-warm) -> scale -> fp8 -> swizzled LDS
//                write + adjq store (for steps 2,3). adj read from HBM exactly once.
//  - k_diffuse:  steps 2,3. Full-D tile 64x256, 512 thr / 8 waves, BK=128, dbuf LDS
//                stage-ahead-1 via global_load_lds(16). adjq read ONCE per step.
// Scales: adjS=256*adj_norm, cS=16*c -> acc=4096*(adj@c); next cS=acc/256; last tap acc/4096.
// Swizzle: 8B chunk within each 64B segment XORed by (row&7); producers pre-swizzle
// global rows so global_load_lds stays linear (rule 21 / m173).

#define BATCH 8
#define NN    2048
#define DD    256
#define REPS  1e-9f
#define SLOPE 0.2f

typedef __bf16 bf16x8_t __attribute__((ext_vector_type(8)));
typedef __bf16 bf16x4_t __attribute__((ext_vector_type(4)));
typedef float  f32x4_t  __attribute__((ext_vector_type(4)));

__device__ __forceinline__ void gl2lds16(const void* g, void* l) {
    __builtin_amdgcn_global_load_lds(
        (const __attribute__((address_space(1))) unsigned int*)(uintptr_t)g,
        (__attribute__((address_space(3))) unsigned int*)(unsigned int)(uintptr_t)l,
        16, 0, 0);
}

__device__ __forceinline__ unsigned int pk_fp8x4(float a, float b, float c, float d) {
    int lo = __builtin_amdgcn_cvt_pk_fp8_f32(a, b, 0, false);
    return (unsigned int)__builtin_amdgcn_cvt_pk_fp8_f32(c, d, lo, true);
}

__device__ __forceinline__ f32x4_t cvt_f32_fp8x4(unsigned int u) {
    f32x4_t r;
    r[0] = __builtin_amdgcn_cvt_f32_fp8(u, 0);
    r[1] = __builtin_amdgcn_cvt_f32_fp8(u, 1);
    r[2] = __builtin_amdgcn_cvt_f32_fp8(u, 2);
    r[3] = __builtin_amdgcn_cvt_f32_fp8(u, 3);
    return r;
}

// swizzled byte position of logical byte n within a row keyed by `key`
__device__ __forceinline__ int swz(int n, int key) {
    return (n & ~63) | ((((n >> 3) & 7) ^ key) << 3) | (n & 7);
}
// byte offset within a 128B LDS row for 8B chunk c (0..15), row r
__device__ __forceinline__ int chunkoff(int c, int r) {
    return ((c >> 3) << 6) | (((c & 7) ^ (r & 7)) << 3);
}

__device__ __forceinline__ uint2 q8(f32x4_t a, f32x4_t b, float sc) {
    uint2 r;
    r.x = pk_fp8x4(a[0] * sc, a[1] * sc, a[2] * sc, a[3] * sc);
    r.y = pk_fp8x4(b[0] * sc, b[1] * sc, b[2] * sc, b[3] * sc);
    return r;
}

// ================= htrans: bf16x3 MFMA; out = cw0*t, c0q = fp8(16t) =================
__global__ __launch_bounds__(256) void k_htrans(const float* __restrict__ h,
                                                const float* __restrict__ W,
                                                const float* __restrict__ convw,
                                                float* __restrict__ out,
                                                unsigned char* __restrict__ c0q) {
    __shared__ __align__(16) __bf16 Ah[64 * 64], Al[64 * 64];
    __shared__ __align__(16) __bf16 Bh[128 * 64], Bl[128 * 64];

    const int tid = threadIdx.x;
    const int n0 = blockIdx.x * 64, o0 = blockIdx.y * 128, b = blockIdx.z;
    const int lane = tid & 63, wv = tid >> 6;
    const int wr = wv >> 1, wc = wv & 1;
    const int rl = lane & 15, kq = lane >> 4;
    const int ar = tid >> 4, ac = (tid & 15) * 4;

    f32x4_t acc[2][4];
#pragma unroll
    for (int i = 0; i < 2; ++i)
#pragma unroll
        for (int j = 0; j < 4; ++j) acc[i][j] = (f32x4_t){0.f, 0.f, 0.f, 0.f};

    for (int kt = 0; kt < 4; ++kt) {
        const int k0 = kt * 64;
#pragma unroll
        for (int q = 0; q < 4; ++q) {
            const int r = q * 16 + ar;
            f32x4_t v = *(const f32x4_t*)(h + ((size_t)b * NN + n0 + r) * DD + k0 + ac);
            bf16x4_t hi4, lo4;
#pragma unroll
            for (int e = 0; e < 4; ++e) {
                float x = v[e];
                __bf16 hh = (__bf16)x;
                hi4[e] = hh;
                lo4[e] = (__bf16)(x - (float)hh);
            }
            const int off = r * 128 + (((ac >> 3) ^ (r & 7)) << 4) + (ac & 7) * 2;
            *(bf16x4_t*)((char*)Ah + off) = hi4;
            *(bf16x4_t*)((char*)Al + off) = lo4;
        }
#pragma unroll
        for (int q = 0; q < 8; ++q) {
            const int r = q * 16 + ar;
            f32x4_t v = *(const f32x4_t*)(W + (size_t)(o0 + r) * DD + k0 + ac);
            bf16x4_t hi4, lo4;
#pragma unroll
            for (int e = 0; e < 4; ++e) {
                float x = v[e];
                __bf16 hh = (__bf16)x;
                hi4[e] = hh;
                lo4[e] = (__bf16)(x - (float)hh);
            }
            const int off = r * 128 + (((ac >> 3) ^ (r & 7)) << 4) + (ac & 7) * 2;
            *(bf16x4_t*)((char*)Bh + off) = hi4;
            *(bf16x4_t*)((char*)Bl + off) = lo4;
        }
        __syncthreads();
#pragma unroll
        for (int s = 0; s < 2; ++s) {
            bf16x8_t ah[2], al[2], bh[4], bl[4];
#pragma unroll
            for (int i = 0; i < 2; ++i) {
                const int row = wr * 32 + i * 16 + rl;
                const int byo = row * 128 + (((s * 4 + kq) ^ (row & 7)) << 4);
                ah[i] = *(const bf16x8_t*)((const char*)Ah + byo);
                al[i] = *(const bf16x8_t*)((const char*)Al + byo);
            }
#pragma unroll
            for (int j = 0; j < 4; ++j) {
                const int o = wc * 64 + j * 16 + rl;
                const int byo = o * 128 + (((s * 4 + kq) ^ (o & 7)) << 4);
                bh[j] = *(const bf16x8_t*)((const char*)Bh + byo);
                bl[j] = *(const bf16x8_t*)((const char*)Bl + byo);
            }
#pragma unroll
            for (int i = 0; i < 2; ++i)
#pragma unroll
                for (int j = 0; j < 4; ++j) {
                    acc[i][j] = __builtin_amdgcn_mfma_f32_16x16x32_bf16(ah[i], bh[j], acc[i][j], 0, 0, 0);
                    acc[i][j] = __builtin_amdgcn_mfma_f32_16x16x32_bf16(al[i], bh[j], acc[i][j], 0, 0, 0);
                    acc[i][j] = __builtin_amdgcn_mfma_f32_16x16x32_bf16(ah[i], bl[j], acc[i][j], 0, 0, 0);
                }
        }
        __syncthreads();
    }

    const float cw0 = convw[0];
#pragma unroll
    for (int i = 0; i < 2; ++i)
#pragma unroll
        for (int j = 0; j < 4; ++j) {
            const int row0 = n0 + wr * 32 + i * 16 + kq * 4;
            const int col  = o0 + wc * 64 + j * 16 + rl;
            float* op = out + ((size_t)b * NN + row0) * DD + col;
#pragma unroll
            for (int r2 = 0; r2 < 4; ++r2) op[r2 * DD] = cw0 * acc[i][j][r2];
            *(unsigned int*)(c0q + ((size_t)b * DD + col) * NN + swz(row0, col & 7)) =
                pk_fp8x4(16.f * acc[i][j][0], 16.f * acc[i][j][1],
                         16.f * acc[i][j][2], 16.f * acc[i][j][3]);
        }
}

// ---------------- shared MFMA core for 64x256 tile, BK=128 ----------------
__device__ __forceinline__ void mfma_step(const unsigned char* Ac, const unsigned char* Bc,
                                          f32x4_t (&acc)[2][4],
                                          int wr, int wc, int rl, int kq) {
#pragma unroll
    for (int s = 0; s < 4; ++s) {
        long a[2], bb[4];
#pragma unroll
        for (int i = 0; i < 2; ++i) {
            const int row = wr * 32 + i * 16 + rl;
            a[i] = *(const long*)(Ac + row * 128 + chunkoff(s * 4 + kq, row));
        }
#pragma unroll
        for (int j = 0; j < 4; ++j) {
            const int o = wc * 64 + j * 16 + rl;
            bb[j] = *(const long*)(Bc + o * 128 + chunkoff(s * 4 + kq, o));
        }
#pragma unroll
        for (int i = 0; i < 2; ++i)
#pragma unroll
            for (int j = 0; j < 4; ++j)
                acc[i][j] = __builtin_amdgcn_mfma_f32_16x16x32_fp8_fp8(a[i], bb[j], acc[i][j], 0, 0, 0);
    }
}

// stage B (256 rows x 128B) via gload_lds: wave wv, 4 issues of 1KB
__device__ __forceinline__ void stage_B(const unsigned char* cRow, unsigned char* Bs,
                                        int wv, int lane, int k0) {
    const int lr = lane >> 3, lc = (lane & 7) * 16;
#pragma unroll
    for (int q = 0; q < 4; ++q)
        gl2lds16(cRow + (size_t)((wv * 4 + q) * 8 + lr) * NN + k0 + lc,
                 Bs + (wv * 4 + q) * 1024);
}

// ================= diffuse1: fused rowsum + quantize + bmm =================
__global__ __launch_bounds__(512) void k_diffuse1(const float* __restrict__ adj,
                                                  const unsigned char* __restrict__ c0q,
                                                  unsigned char* __restrict__ adjq,
                                                  unsigned char* __restrict__ c1q) {
    __shared__ __align__(16) unsigned char As[2][64 * 128];    // 16 KB
    __shared__ __align__(16) unsigned char Bs[2][256 * 128];   // 64 KB
    __shared__ float inv_s[64];

    const int tid = threadIdx.x;
    const int n0 = blockIdx.x * 64, b = blockIdx.y;
    const int lane = tid & 63, wv = tid >> 6;
    const int wr = wv >> 2, wc = wv & 3;
    const int rl = lane & 15, kq = lane >> 4;

    const float* aF = adj + ((size_t)b * NN + n0) * NN;
    unsigned char* aqRow = adjq + ((size_t)b * NN + n0) * NN;
    const unsigned char* cRow = c0q + (size_t)b * DD * NN;

    // ---- phase 0: rowsums (wave wv handles rows [wv*8, wv*8+8)) ----
#pragma unroll
    for (int rr = 0; rr < 8; ++rr) {
        const int r = wv * 8 + rr;
        const float* rp = aF + (size_t)r * NN;
        float s = 0.f;
#pragma unroll
        for (int j = 0; j < 8; ++j) {
            f32x4_t v = *(const f32x4_t*)(rp + (j * 64 + lane) * 4);
            s += v[0] + v[1] + v[2] + v[3];
        }
#pragma unroll
        for (int m = 1; m < 64; m <<= 1) s += __shfl_xor(s, m, 64);
        if (lane == 0) inv_s[r] = 256.0f / (s + REPS);
    }
    __syncthreads();

    // ---- A staging assignment: thread -> row r_ (0..63), chunks {c_, c_+8} ----
    const int r_ = tid >> 3, c_ = tid & 7;
    const float* rp_ = aF + (size_t)r_ * NN;
    const float sc_r = inv_s[r_];
    const int key = r_ & 7;

    f32x4_t acc[2][4];
#pragma unroll
    for (int i = 0; i < 2; ++i)
#pragma unroll
        for (int j = 0; j < 4; ++j) acc[i][j] = (f32x4_t){0.f, 0.f, 0.f, 0.f};

    // prologue: tile 0
    {
        f32x4_t rv0 = *(const f32x4_t*)(rp_ + c_ * 8);
        f32x4_t rv1 = *(const f32x4_t*)(rp_ + c_ * 8 + 4);
        f32x4_t rv2 = *(const f32x4_t*)(rp_ + (c_ + 8) * 8);
        f32x4_t rv3 = *(const f32x4_t*)(rp_ + (c_ + 8) * 8 + 4);
        stage_B(cRow, Bs[0], wv, lane, 0);
        uint2 u0 = q8(rv0, rv1, sc_r);
        uint2 u1 = q8(rv2, rv3, sc_r);
        *(uint2*)(As[0] + r_ * 128 + chunkoff(c_, r_)) = u0;
        *(uint2*)(As[0] + r_ * 128 + chunkoff(c_ + 8, r_)) = u1;
        *(uint2*)(aqRow + (size_t)r_ * NN + swz(c_ * 8, key)) = u0;
        *(uint2*)(aqRow + (size_t)r_ * NN + swz((c_ + 8) * 8, key)) = u1;
    }
    __syncthreads();

    for (int t = 0; t < 16; ++t) {
        const int pb = t & 1;
        f32x4_t rv0, rv1, rv2, rv3;
        if (t < 15) {
            const int k1 = (t + 1) * 128;
            rv0 = *(const f32x4_t*)(rp_ + k1 + c_ * 8);
            rv1 = *(const f32x4_t*)(rp_ + k1 + c_ * 8 + 4);
            rv2 = *(const f32x4_t*)(rp_ + k1 + (c_ + 8) * 8);
            rv3 = *(const f32x4_t*)(rp_ + k1 + (c_ + 8) * 8 + 4);
            stage_B(cRow, Bs[pb ^ 1], wv, lane, k1);
        }
        mfma_step(As[pb], Bs[pb], acc, wr, wc, rl, kq);
        if (t < 15) {
            const int k1 = (t + 1) * 128;
            uint2 u0 = q8(rv0, rv1, sc_r);
            uint2 u1 = q8(rv2, rv3, sc_r);
            *(uint2*)(As[pb ^ 1] + r_ * 128 + chunkoff(c_, r_)) = u0;
            *(uint2*)(As[pb ^ 1] + r_ * 128 + chunkoff(c_ + 8, r_)) = u1;
            *(uint2*)(aqRow + (size_t)r_ * NN + swz(k1 + c_ * 8, key)) = u0;
            *(uint2*)(aqRow + (size_t)r_ * NN + swz(k1 + (c_ + 8) * 8, key)) = u1;
        }
        __syncthreads();
    }

    // ---- epilogue: c1q = fp8(acc/256) ----
#pragma unroll
    for (int i = 0; i < 2; ++i)
#pragma unroll
        for (int j = 0; j < 4; ++j) {
            const int row0 = n0 + wr * 32 + i * 16 + kq * 4;
            const int col  = wc * 64 + j * 16 + rl;
            const float rs = 1.0f / 256.0f;
            *(unsigned int*)(c1q + ((size_t)b * DD + col) * NN + swz(row0, col & 7)) =
                pk_fp8x4(rs * acc[i][j][0], rs * acc[i][j][1],
                         rs * acc[i][j][2], rs * acc[i][j][3]);
        }
}

// ================= diffuse steps 2,3: full gload_lds, 64x256 tile =================
template <bool LAST>
__global__ __launch_bounds__(512) void k_diffuse(const unsigned char* __restrict__ adjq,
                                                 const unsigned char* __restrict__ cinq,
                                                 unsigned char* __restrict__ coutq,
                                                 const unsigned char* __restrict__ c1q,
                                                 const unsigned char* __restrict__ c2q,
                                                 float* __restrict__ out,
                                                 const float* __restrict__ convw,
                                                 const float* __restrict__ convb) {
    __shared__ __align__(16) unsigned char As[2][64 * 128];    // 16 KB
    __shared__ __align__(16) unsigned char Bs[2][256 * 128];   // 64 KB

    const int tid = threadIdx.x;
    const int n0 = blockIdx.x * 64, b = blockIdx.y;
    const int lane = tid & 63, wv = tid >> 6;
    const int wr = wv >> 2, wc = wv & 3;
    const int rl = lane & 15, kq = lane >> 4;
    const int lr = lane >> 3, lc = (lane & 7) * 16;

    const unsigned char* aRow = adjq + ((size_t)b * NN + n0) * NN;
    const unsigned char* cRow = cinq + (size_t)b * DD * NN;

    f32x4_t acc[2][4];
#pragma unroll
    for (int i = 0; i < 2; ++i)
#pragma unroll
        for (int j = 0; j < 4; ++j) acc[i][j] = (f32x4_t){0.f, 0.f, 0.f, 0.f};

    // A: 8KB, wave wv -> rows [wv*8, wv*8+8)
    gl2lds16(aRow + (size_t)(wv * 8 + lr) * NN + lc, As[0] + wv * 1024);
    stage_B(cRow, Bs[0], wv, lane, 0);
    __syncthreads();

    for (int t = 0; t < 16; ++t) {
        const int pb = t & 1;
        if (t < 15) {
            const int k1 = (t + 1) * 128;
            gl2lds16(aRow + (size_t)(wv * 8 + lr) * NN + k1 + lc, As[pb ^ 1] + wv * 1024);
            stage_B(cRow, Bs[pb ^ 1], wv, lane, k1);
        }
        mfma_step(As[pb], Bs[pb], acc, wr, wc, rl, kq);
        __syncthreads();
    }

#pragma unroll
    for (int i = 0; i < 2; ++i)
#pragma unroll
        for (int j = 0; j < 4; ++j) {
            const int row0 = n0 + wr * 32 + i * 16 + kq * 4;
            const int col  = wc * 64 + j * 16 + rl;
            if (LAST) {
                const float cw1 = convw[1], cw2 = convw[2], cw3 = convw[3];
                const float cb  = convb[0];
                const float ru = 1.0f / 16.0f, rf = 1.0f / 4096.0f;
                float* op = out + ((size_t)b * NN + row0) * DD + col;
                const int sa = swz(row0, col & 7);
                f32x4_t u1 = cvt_f32_fp8x4(*(const unsigned int*)(c1q + ((size_t)b * DD + col) * NN + sa));
                f32x4_t u2 = cvt_f32_fp8x4(*(const unsigned int*)(c2q + ((size_t)b * DD + col) * NN + sa));
#pragma unroll
                for (int r2 = 0; r2 < 4; ++r2) {
                    float v = op[r2 * DD] + cw1 * ru * u1[r2] + cw2 * ru * u2[r2]
                            + cw3 * rf * acc[i][j][r2] + cb;
                    op[r2 * DD] = v >= 0.0f ? v : SLOPE * v;
                }
            } else {
                const float rs = 1.0f / 256.0f;
                *(unsigned int*)(coutq + ((size_t)b * DD + col) * NN + swz(row0, col & 7)) =
                    pk_fp8x4(rs * acc[i][j][0], rs * acc[i][j][1],
                             rs * acc[i][j][2], rs * acc[i][j][3]);
            }
        }
}

extern "C" void kernel_launch(void* const* d_in, const int* in_sizes, int n_in,
                              void* d_out, int out_size, void* d_ws, size_t ws_size,
                              hipStream_t stream) {
    const float* h   = (const float*)d_in[0];
    const float* adj = (const float*)d_in[1];
    const float* W   = (const float*)d_in[2];
    const float* cw  = (const float*)d_in[3];
    const float* cb  = (const float*)d_in[4];
    float* out = (float*)d_out;

    char* ws = (char*)d_ws;
    unsigned char* adjq = (unsigned char*)ws;                         // 32 MB
    unsigned char* c0q  = (unsigned char*)(ws + 33554432);            // 4 MB
    unsigned char* c1q  = (unsigned char*)(ws + 33554432 + 4194304);  // 4 MB
    unsigned char* c2q  = (unsigned char*)(ws + 33554432 + 8388608);  // 4 MB (~44 MB)

    k_htrans<<<dim3(NN / 64, DD / 128, BATCH), 256, 0, stream>>>(h, W, cw, out, c0q);
    k_diffuse1<<<dim3(NN / 64, BATCH), 512, 0, stream>>>(adj, c0q, adjq, c1q);
    k_diffuse<false><<<dim3(NN / 64, BATCH), 512, 0, stream>>>(adjq, c1q, c2q, nullptr, nullptr, out, cw, cb);
    k_diffuse<true ><<<dim3(NN / 64, BATCH), 512, 0, stream>>>(adjq, c2q, nullptr, c1q, c2q, out, cw, cb);
}

// Round 7
// 113.282 us; speedup vs baseline: 1.0833x; 1.0833x over previous
//
#include <hip/hip_runtime.h>
#include <hip/hip_bf16.h>
#include <cstdint>

// MultiRelationalGraphDiffusion: out = LeakyReLU( sum_k conv_w[k] * (adj_norm^k @ (h@W^T)) + conv_b )
// B=8, N=2048, D=256, K=4.
//
// Round-7: revert R6's diffuse1 fusion (80us latency-bound disaster: 1 blk/CU, 21% occ).
// Keep R5's roofline-bound normadj (wave-per-row, 166MB @ ~6.3TB/s) and htrans.
// Diffuse: 64x128 tile, BK=64, but now 4 LDS buffers + stage-ahead-2 with COUNTED
// vmcnt (T4): iter t stages tile (t+2)%32, waits vmcnt(6) (leaves t+1,t+2 in flight),
// raw s_barrier + sched_barrier(0). Loads get ~2 K-steps to land instead of being
// drained by __syncthreads every tile (the structural ~20% stall, here dominant).
// Ledger: NBUF=4 >= S+2: buffer (t+2)&3 written at iter t was last read at t-2;
// issuing wave passed barrier(t-1) => all waves finished compute(t-2). Wrapped
// staging keeps the vmcnt immediate constant.
// Scales: adjS=256*adj_norm, cS=16*c -> acc=4096*(adj@c); next cS=acc/256; last tap acc/4096.

#define BATCH 8
#define NN    2048
#define DD    256
#define REPS  1e-9f
#define SLOPE 0.2f

typedef __bf16 bf16x8_t __attribute__((ext_vector_type(8)));
typedef __bf16 bf16x4_t __attribute__((ext_vector_type(4)));
typedef float  f32x4_t  __attribute__((ext_vector_type(4)));

__device__ __forceinline__ void gl2lds16(const void* g, void* l) {
    __builtin_amdgcn_global_load_lds(
        (const __attribute__((address_space(1))) unsigned int*)(uintptr_t)g,
        (__attribute__((address_space(3))) unsigned int*)(unsigned int)(uintptr_t)l,
        16, 0, 0);
}

__device__ __forceinline__ unsigned int pk_fp8x4(float a, float b, float c, float d) {
    int lo = __builtin_amdgcn_cvt_pk_fp8_f32(a, b, 0, false);
    return (unsigned int)__builtin_amdgcn_cvt_pk_fp8_f32(c, d, lo, true);
}

__device__ __forceinline__ f32x4_t cvt_f32_fp8x4(unsigned int u) {
    f32x4_t r;
    r[0] = __builtin_amdgcn_cvt_f32_fp8(u, 0);
    r[1] = __builtin_amdgcn_cvt_f32_fp8(u, 1);
    r[2] = __builtin_amdgcn_cvt_f32_fp8(u, 2);
    r[3] = __builtin_amdgcn_cvt_f32_fp8(u, 3);
    return r;
}

// swizzled byte position of logical byte n within a row keyed by `key`
__device__ __forceinline__ int swz(int n, int key) {
    return (n & ~63) | ((((n >> 3) & 7) ^ key) << 3) | (n & 7);
}

// ================= normadj: wave-per-row, no LDS, fp8 x256 output =================
__global__ __launch_bounds__(256) void k_normadj(const float* __restrict__ adj,
                                                 unsigned char* __restrict__ adjq) {
    const int l = threadIdx.x & 63;
    const int row = blockIdx.x * 4 + (threadIdx.x >> 6);   // b*NN + n
    const float* src = adj + (size_t)row * NN;
    f32x4_t v[8];
#pragma unroll
    for (int j = 0; j < 8; ++j) v[j] = *(const f32x4_t*)(src + (j * 64 + l) * 4);
    float s = 0.f;
#pragma unroll
    for (int j = 0; j < 8; ++j) s += v[j][0] + v[j][1] + v[j][2] + v[j][3];
#pragma unroll
    for (int m = 1; m < 64; m <<= 1) s += __shfl_xor(s, m, 64);
    const float sc = 256.0f / (s + REPS);
    const int key = row & 7;
    unsigned char* drow = adjq + (size_t)row * NN;
#pragma unroll
    for (int j = 0; j < 8; ++j) {
        const int n = (j * 64 + l) * 4;
        *(unsigned int*)(drow + swz(n, key)) =
            pk_fp8x4(v[j][0] * sc, v[j][1] * sc, v[j][2] * sc, v[j][3] * sc);
    }
}

// ================= htrans: bf16x3 MFMA; out = cw0*t, c0q = fp8(16t) =================
__global__ __launch_bounds__(256) void k_htrans(const float* __restrict__ h,
                                                const float* __restrict__ W,
                                                const float* __restrict__ convw,
                                                float* __restrict__ out,
                                                unsigned char* __restrict__ c0q) {
    __shared__ __align__(16) __bf16 Ah[64 * 64], Al[64 * 64];
    __shared__ __align__(16) __bf16 Bh[128 * 64], Bl[128 * 64];

    const int tid = threadIdx.x;
    const int n0 = blockIdx.x * 64, o0 = blockIdx.y * 128, b = blockIdx.z;
    const int lane = tid & 63, wv = tid >> 6;
    const int wr = wv >> 1, wc = wv & 1;
    const int rl = lane & 15, kq = lane >> 4;
    const int ar = tid >> 4, ac = (tid & 15) * 4;

    f32x4_t acc[2][4];
#pragma unroll
    for (int i = 0; i < 2; ++i)
#pragma unroll
        for (int j = 0; j < 4; ++j) acc[i][j] = (f32x4_t){0.f, 0.f, 0.f, 0.f};

    for (int kt = 0; kt < 4; ++kt) {
        const int k0 = kt * 64;
#pragma unroll
        for (int q = 0; q < 4; ++q) {
            const int r = q * 16 + ar;
            f32x4_t v = *(const f32x4_t*)(h + ((size_t)b * NN + n0 + r) * DD + k0 + ac);
            bf16x4_t hi4, lo4;
#pragma unroll
            for (int e = 0; e < 4; ++e) {
                float x = v[e];
                __bf16 hh = (__bf16)x;
                hi4[e] = hh;
                lo4[e] = (__bf16)(x - (float)hh);
            }
            const int off = r * 128 + (((ac >> 3) ^ (r & 7)) << 4) + (ac & 7) * 2;
            *(bf16x4_t*)((char*)Ah + off) = hi4;
            *(bf16x4_t*)((char*)Al + off) = lo4;
        }
#pragma unroll
        for (int q = 0; q < 8; ++q) {
            const int r = q * 16 + ar;
            f32x4_t v = *(const f32x4_t*)(W + (size_t)(o0 + r) * DD + k0 + ac);
            bf16x4_t hi4, lo4;
#pragma unroll
            for (int e = 0; e < 4; ++e) {
                float x = v[e];
                __bf16 hh = (__bf16)x;
                hi4[e] = hh;
                lo4[e] = (__bf16)(x - (float)hh);
            }
            const int off = r * 128 + (((ac >> 3) ^ (r & 7)) << 4) + (ac & 7) * 2;
            *(bf16x4_t*)((char*)Bh + off) = hi4;
            *(bf16x4_t*)((char*)Bl + off) = lo4;
        }
        __syncthreads();
#pragma unroll
        for (int s = 0; s < 2; ++s) {
            bf16x8_t ah[2], al[2], bh[4], bl[4];
#pragma unroll
            for (int i = 0; i < 2; ++i) {
                const int row = wr * 32 + i * 16 + rl;
                const int byo = row * 128 + (((s * 4 + kq) ^ (row & 7)) << 4);
                ah[i] = *(const bf16x8_t*)((const char*)Ah + byo);
                al[i] = *(const bf16x8_t*)((const char*)Al + byo);
            }
#pragma unroll
            for (int j = 0; j < 4; ++j) {
                const int o = wc * 64 + j * 16 + rl;
                const int byo = o * 128 + (((s * 4 + kq) ^ (o & 7)) << 4);
                bh[j] = *(const bf16x8_t*)((const char*)Bh + byo);
                bl[j] = *(const bf16x8_t*)((const char*)Bl + byo);
            }
#pragma unroll
            for (int i = 0; i < 2; ++i)
#pragma unroll
                for (int j = 0; j < 4; ++j) {
                    acc[i][j] = __builtin_amdgcn_mfma_f32_16x16x32_bf16(ah[i], bh[j], acc[i][j], 0, 0, 0);
                    acc[i][j] = __builtin_amdgcn_mfma_f32_16x16x32_bf16(al[i], bh[j], acc[i][j], 0, 0, 0);
                    acc[i][j] = __builtin_amdgcn_mfma_f32_16x16x32_bf16(ah[i], bl[j], acc[i][j], 0, 0, 0);
                }
        }
        __syncthreads();
    }

    const float cw0 = convw[0];
#pragma unroll
    for (int i = 0; i < 2; ++i)
#pragma unroll
        for (int j = 0; j < 4; ++j) {
            const int row0 = n0 + wr * 32 + i * 16 + kq * 4;
            const int col  = o0 + wc * 64 + j * 16 + rl;
            float* op = out + ((size_t)b * NN + row0) * DD + col;
#pragma unroll
            for (int r2 = 0; r2 < 4; ++r2) op[r2 * DD] = cw0 * acc[i][j][r2];
            *(unsigned int*)(c0q + ((size_t)b * DD + col) * NN + swz(row0, col & 7)) =
                pk_fp8x4(16.f * acc[i][j][0], 16.f * acc[i][j][1],
                         16.f * acc[i][j][2], 16.f * acc[i][j][3]);
        }
}

// ================= diffusion step (fp8, 4-buffer, stage-ahead-2, counted vmcnt) =================
// per wave per tile: 1 A-load + 2 B-loads (1KB each) -> L=3; wait leaves 2L=6 in flight.
__device__ __forceinline__ void stage_tile_q(const unsigned char* __restrict__ aRow,
                                             const unsigned char* __restrict__ cRow,
                                             unsigned char* As, unsigned char* Bs,
                                             int wv, int sr, int sb, int k0) {
    gl2lds16(aRow + (size_t)(wv * 16 + sr) * NN + k0 + sb, As + wv * 1024);
#pragma unroll
    for (int q = 0; q < 2; ++q)
        gl2lds16(cRow + (size_t)((wv * 2 + q) * 16 + sr) * NN + k0 + sb,
                 Bs + (wv * 2 + q) * 1024);
}

template <bool LAST>
__global__ __launch_bounds__(256) void k_diffuse(const unsigned char* __restrict__ adjq,
                                                 const unsigned char* __restrict__ cinq,
                                                 unsigned char* __restrict__ coutq,
                                                 const unsigned char* __restrict__ c1q,
                                                 const unsigned char* __restrict__ c2q,
                                                 float* __restrict__ out,
                                                 const float* __restrict__ convw,
                                                 const float* __restrict__ convb) {
    __shared__ __align__(16) unsigned char As[4][64 * 64];    // 4 x 4 KB
    __shared__ __align__(16) unsigned char Bs[4][128 * 64];   // 4 x 8 KB  (48 KB total)

    const int tid = threadIdx.x;
    const int n0 = blockIdx.x * 64, o0 = blockIdx.y * 128, b = blockIdx.z;
    const int lane = tid & 63, wv = tid >> 6;
    const int wr = wv >> 1, wc = wv & 1;
    const int rl = lane & 15, kq = lane >> 4;
    const int sr = lane >> 2, sb = (lane & 3) * 16;

    const unsigned char* aRow = adjq + (size_t)b * NN * NN + (size_t)n0 * NN;
    const unsigned char* cRow = cinq + (size_t)b * DD * NN + (size_t)o0 * NN;

    f32x4_t acc[2][4];
#pragma unroll
    for (int i = 0; i < 2; ++i)
#pragma unroll
        for (int j = 0; j < 4; ++j) acc[i][j] = (f32x4_t){0.f, 0.f, 0.f, 0.f};

    // prologue: stage tiles 0,1
    stage_tile_q(aRow, cRow, As[0], Bs[0], wv, sr, sb, 0);
    stage_tile_q(aRow, cRow, As[1], Bs[1], wv, sr, sb, 64);

    for (int t = 0; t < 32; ++t) {
        // stage tile (t+2)%32 into buf (t+2)&3 (wraps at the tail: rewrites stale bufs,
        // keeps the vmcnt immediate constant at 6)
        stage_tile_q(aRow, cRow, As[(t + 2) & 3], Bs[(t + 2) & 3],
                     wv, sr, sb, ((t + 2) & 31) * 64);
        asm volatile("s_waitcnt vmcnt(6)" ::: "memory");   // tile t's 3 loads landed
        __builtin_amdgcn_s_barrier();                      // all waves' tile-t loads landed
        __builtin_amdgcn_sched_barrier(0);                 // keep ds_reads below (rule 18)
        const unsigned char* Ac = As[t & 3];
        const unsigned char* Bc = Bs[t & 3];
#pragma unroll
        for (int s = 0; s < 2; ++s) {
            long a[2], bb[4];
#pragma unroll
            for (int i = 0; i < 2; ++i) {
                const int row = wr * 32 + i * 16 + rl;
                a[i] = *(const long*)(Ac + row * 64 + (((s * 4 + kq) ^ (row & 7)) << 3));
            }
#pragma unroll
            for (int j = 0; j < 4; ++j) {
                const int o = wc * 64 + j * 16 + rl;
                bb[j] = *(const long*)(Bc + o * 64 + (((s * 4 + kq) ^ (o & 7)) << 3));
            }
#pragma unroll
            for (int i = 0; i < 2; ++i)
#pragma unroll
                for (int j = 0; j < 4; ++j)
                    acc[i][j] = __builtin_amdgcn_mfma_f32_16x16x32_fp8_fp8(a[i], bb[j], acc[i][j], 0, 0, 0);
        }
        // no trailing barrier: a wave issuing into buf (t+3)&3 at iter t+1 has passed
        // barrier(t) => every wave finished compute(t-1); (t+3)&3 was last read at t-1.
    }

    // ---- epilogue ----
#pragma unroll
    for (int i = 0; i < 2; ++i)
#pragma unroll
        for (int j = 0; j < 4; ++j) {
            const int row0 = n0 + wr * 32 + i * 16 + kq * 4;
            const int col  = o0 + wc * 64 + j * 16 + rl;
            if (LAST) {
                const float cw1 = convw[1], cw2 = convw[2], cw3 = convw[3];
                const float cb  = convb[0];
                const float ru = 1.0f / 16.0f, rf = 1.0f / 4096.0f;
                float* op = out + ((size_t)b * NN + row0) * DD + col;
                const int sa = swz(row0, col & 7);
                f32x4_t u1 = cvt_f32_fp8x4(*(const unsigned int*)(c1q + ((size_t)b * DD + col) * NN + sa));
                f32x4_t u2 = cvt_f32_fp8x4(*(const unsigned int*)(c2q + ((size_t)b * DD + col) * NN + sa));
#pragma unroll
                for (int r2 = 0; r2 < 4; ++r2) {
                    float v = op[r2 * DD] + cw1 * ru * u1[r2] + cw2 * ru * u2[r2]
                            + cw3 * rf * acc[i][j][r2] + cb;
                    op[r2 * DD] = v >= 0.0f ? v : SLOPE * v;
                }
            } else {
                const float rs = 1.0f / 256.0f;   // acc -> 16*c_next
                *(unsigned int*)(coutq + ((size_t)b * DD + col) * NN + swz(row0, col & 7)) =
                    pk_fp8x4(rs * acc[i][j][0], rs * acc[i][j][1],
                             rs * acc[i][j][2], rs * acc[i][j][3]);
            }
        }
}

extern "C" void kernel_launch(void* const* d_in, const int* in_sizes, int n_in,
                              void* d_out, int out_size, void* d_ws, size_t ws_size,
                              hipStream_t stream) {
    const float* h   = (const float*)d_in[0];
    const float* adj = (const float*)d_in[1];
    const float* W   = (const float*)d_in[2];
    const float* cw  = (const float*)d_in[3];
    const float* cb  = (const float*)d_in[4];
    float* out = (float*)d_out;

    char* ws = (char*)d_ws;
    unsigned char* adjq = (unsigned char*)ws;                         // 32 MB
    unsigned char* c0q  = (unsigned char*)(ws + 33554432);            // 4 MB
    unsigned char* c1q  = (unsigned char*)(ws + 33554432 + 4194304);  // 4 MB
    unsigned char* c2q  = (unsigned char*)(ws + 33554432 + 8388608);  // 4 MB (~44 MB)

    k_normadj<<<BATCH * NN / 4, 256, 0, stream>>>(adj, adjq);
    k_htrans<<<dim3(NN / 64, DD / 128, BATCH), 256, 0, stream>>>(h, W, cw, out, c0q);
    k_diffuse<false><<<dim3(NN / 64, DD / 128, BATCH), 256, 0, stream>>>(adjq, c0q, c1q, nullptr, nullptr, out, cw, cb);
    k_diffuse<false><<<dim3(NN / 64, DD / 128, BATCH), 256, 0, stream>>>(adjq, c1q, c2q, nullptr, nullptr, out, cw, cb);
    k_diffuse<true ><<<dim3(NN / 64, DD / 128, BATCH), 256, 0, stream>>>(adjq, c2q, nullptr, c1q, c2q, out, cw, cb);
}